// Round 4
// baseline (740.945 us; speedup 1.0000x reference)
//
#include <hip/hip_runtime.h>
#include <hip/hip_bf16.h>

#define BATCH 32
#define CIN   256
#define OCH   256
#define HW    56
#define PW    58
#define PAREA (PW*PW)   /* 3364 */
#define PLANE (HW*HW)   /* 3136 */

typedef float float4v __attribute__((ext_vector_type(4)));
typedef short short8  __attribute__((ext_vector_type(8)));
typedef short short4v __attribute__((ext_vector_type(4)));

__device__ __forceinline__ unsigned short f2bf(float f) {
  union { float f; unsigned u; } v; v.f = f;
  unsigned r = v.u + 0x7fffu + ((v.u >> 16) & 1u);
  return (unsigned short)(r >> 16);
}

// async global->LDS, 16B per lane, LDS dest linear in lane order
__device__ __forceinline__ void gll16(const unsigned short* g, unsigned short* l) {
  __builtin_amdgcn_global_load_lds(
      (const __attribute__((address_space(1))) void*)g,
      (__attribute__((address_space(3))) void*)l,
      16, 0, 0);
}

// ---------------- Kernel 1: fused pool (avg+max 56x56->5x5) + xp prep -----------
// block = (b, group of 4 channels), 512 thr, 50KB LDS -> 3 blocks/CU.
// Grid XCD-chunked so the 8 blocks sharing each xp 64B line sit on one XCD.
__global__ __launch_bounds__(512) void poolprep_kernel(
    const float* __restrict__ x, float* __restrict__ avgp,
    float* __restrict__ maxp, unsigned short* __restrict__ xp) {
  __shared__ float pl[4][3140];
  int p = blockIdx.x;                 // 2048 = 8 XCD * 256
  int L = (p & 7) * 256 + (p >> 3);
  int cg = L & 63, b = L >> 6;        // channels cg*4 .. cg*4+3
  int tid = threadIdx.x;
  const float* src = x + ((size_t)(b * 256 + cg * 4)) * PLANE;

  // load 4 planes (3136 float4), up to 7 in flight per thread
  float4v v[7];
#pragma unroll
  for (int k = 0; k < 7; ++k) {
    int e = tid + k * 512;
    if (e < 3136) v[k] = *(const float4v*)&src[(size_t)(e / 784) * PLANE + (e % 784) * 4];
  }
#pragma unroll
  for (int k = 0; k < 7; ++k) {
    int e = tid + k * 512;
    if (e < 3136) *(float4v*)&pl[e / 784][(e % 784) * 4] = v[k];
  }
  __syncthreads();

  // pool: 4 channels x 25 bins, bit-identical loop to reference
  if (tid < 100) {
    int c = tid / 25, bin = tid % 25;
    int i = bin / 5, j = bin % 5;
    int r0 = (i * HW) / 5, r1 = ((i + 1) * HW + 4) / 5;
    int c0 = (j * HW) / 5, c1 = ((j + 1) * HW + 4) / 5;
    float s = 0.f, m = -1e30f;
    for (int r = r0; r < r1; ++r)
      for (int c2 = c0; c2 < c1; ++c2) {
        float vv = pl[c][r * HW + c2];
        s += vv; m = fmaxf(m, vv);
      }
    size_t o = ((size_t)(b * 256 + cg * 4 + c)) * 25 + bin;
    avgp[o] = s / (float)((r1 - r0) * (c1 - c0));
    maxp[o] = m;
  }

  // xp: bf16 [b][pos][ic], swizzled: 8-elem chunk c stored at c ^ ((pos>>1)&3)
  int ch0 = cg * 4;
  int g32 = ch0 >> 5;            // which 32-ic group
  int cc = (ch0 >> 3) & 3;       // logical chunk within group
  int half = (ch0 >> 2) & 1;     // which half of the 8-chunk
  for (int pi = tid; pi < PLANE; pi += 512) {
    int y = pi / 56, col = pi % 56;
    int pos = (y + 1) * PW + (col + 1);
    short4v w4;
#pragma unroll
    for (int k = 0; k < 4; ++k) w4[k] = (short)f2bf(pl[k][pi]);
    int cph = cc ^ ((pos >> 1) & 3);
    *(short4v*)&xp[((size_t)b * PAREA + pos) * 256 + g32 * 32 + cph * 8 + half * 4] = w4;
  }
}

// ---------------- Kernel 2: dynamic weight computation ----------------
// Wbf layout: tiles [b][ocb2][icb8][r9] of [oc 128][ic 32] (8KB/tile)
__global__ __launch_bounds__(256) void wcalc_kernel(
    const float* __restrict__ avgp, const float* __restrict__ maxp,
    const float* __restrict__ w1, const float* __restrict__ b1,
    const float* __restrict__ w2, const float* __restrict__ b2,
    const float* __restrict__ watt, const float* __restrict__ batt,
    unsigned short* __restrict__ Wbf) {
  int blk = blockIdx.x;
  int oc = blk & 255, b = blk >> 8;
  __shared__ float s_avg[25], s_max[25], s_w1[9], s_wgt1[9];
  int tid = threadIdx.x;
  size_t base = ((size_t)b * 256 + oc) * 25;
  if (tid < 25) { s_avg[tid] = avgp[base + tid]; s_max[tid] = maxp[base + tid]; }
  if (tid >= 32 && tid < 41) s_w1[tid - 32] = w1[oc * 9 + (tid - 32)];
  __syncthreads();
  if (tid < 9) {
    int ky = tid / 3, kx = tid % 3;
    float acc = b1[oc];
    for (int u = 0; u < 3; ++u)
      for (int v = 0; v < 3; ++v)
        acc += s_avg[(ky + u) * 5 + kx + v] * s_w1[u * 3 + v];
    s_wgt1[tid] = fmaxf(acc, 0.f);
  }
  __syncthreads();
  int ic = tid;
  size_t g = (size_t)oc * 256 + ic;
  float wa[9];
#pragma unroll
  for (int r = 0; r < 9; ++r) wa[r] = watt[g * 9 + r];
  float ba = batt[g], w2v = w2[g], b2v = b2[g];

  int ocb = oc >> 7, ocl = oc & 127;
  int icb = ic >> 5;
  size_t tilebase = ((size_t)((b * 2 + ocb) * 8 + icb)) * 9;   // tile units
  size_t elem = (size_t)ocl * 32 + (ic & 31);

#pragma unroll
  for (int r = 0; r < 9; ++r) {
    int ky = r / 3, kx = r % 3;
    float s = ba;
#pragma unroll
    for (int u = 0; u < 3; ++u)
#pragma unroll
      for (int v = 0; v < 3; ++v)
        s += s_max[(ky + u) * 5 + kx + v] * wa[u * 3 + v];
    float att = 1.f / (1.f + __expf(-s));
    float wv = (s_wgt1[r] * w2v + b2v) * att;
    Wbf[(tilebase + r) * 4096 + elem] = f2bf(wv);
  }
}

// ---------------- Kernel 3a: zero the padded border of xp ----------------
__global__ __launch_bounds__(256) void border_kernel(unsigned short* __restrict__ xp) {
  int bid = blockIdx.x;           // 32 * 228
  int b = bid / 228, bi = bid % 228;
  int pos;
  if (bi < 58)       pos = bi;
  else if (bi < 116) pos = 57 * PW + (bi - 58);
  else if (bi < 172) pos = (bi - 116 + 1) * PW;
  else               pos = (bi - 172 + 1) * PW + 57;
  xp[((size_t)b * PAREA + pos) * 256 + threadIdx.x] = 0;
}

// ---------------- Kernel 4: dynamic conv via MFMA ------------------------------
// A: explicit 2-deep register pipeline from global (L2-resident, coalesced);
// B: LDS double-buffered via global_load_lds; ONE barrier per icb.
__global__ __launch_bounds__(256, 2) void conv_kernel(
    const unsigned short* __restrict__ xp,
    const unsigned short* __restrict__ Wbf,
    float* __restrict__ out) {
  __shared__ unsigned short bpl[2][348 * 32];  // 2 x 22272 B, swizzled layout

  int p = blockIdx.x;
  int L = (p & 7) * 112 + (p >> 3);   // XCD-chunked: 4 batches per XCD
  int rt = L % 14; int t2 = L / 14; int ocb = t2 & 1; int b = t2 >> 1;
  int y0 = rt * 4;
  int tid = threadIdx.x;
  int lane = tid & 63, w = tid >> 6;
  int mw = w & 1, nw = w >> 1;     // 2 M-waves x 2 N-waves
  int quad = lane >> 4, l16 = lane & 15;

  int basepos[7];
#pragma unroll
  for (int nt = 0; nt < 7; ++nt) {
    int n = nw * 112 + nt * 16 + l16;
    basepos[nt] = (n / 56) * PW + (n % 56);
  }

  float4v acc[4][7];
#pragma unroll
  for (int mt = 0; mt < 4; ++mt)
#pragma unroll
    for (int nt = 0; nt < 7; ++nt)
      acc[mt][nt] = (float4v){0.f, 0.f, 0.f, 0.f};

  const size_t xbase = ((size_t)b * PAREA + (size_t)y0 * PW) * 256;
  const unsigned short* wb = Wbf + (size_t)((b * 2 + ocb) * 72) * 4096;
  const int aoff = (mw * 64 + l16) * 32 + quad * 8;   // + mt*512 per m-tile

  // prologue: stage bpl[0] (icb=0) + preload A slices kk=0 (afA), kk=1 (afB)
  for (int e = tid; e < 1392; e += 256)
    gll16(&xp[xbase + (size_t)(e >> 2) * 256 + (e & 3) * 8], &bpl[0][e * 8]);
  short8 afA0, afA1, afA2, afA3, afB0, afB1, afB2, afB3;
  {
    const unsigned short* w0p = wb + aoff;
    afA0 = *(const short8*)&w0p[0];    afA1 = *(const short8*)&w0p[512];
    afA2 = *(const short8*)&w0p[1024]; afA3 = *(const short8*)&w0p[1536];
    const unsigned short* w1p = wb + 4096 + aoff;
    afB0 = *(const short8*)&w1p[0];    afB1 = *(const short8*)&w1p[512];
    afB2 = *(const short8*)&w1p[1024]; afB3 = *(const short8*)&w1p[1536];
  }
  __syncthreads();

  // One r-step: ds_read 7 bfrags, 4x7 MFMA; after the MFMAs that consume
  // register set S##mt, immediately re-load it with slice kk+2 (same parity).
#define RSTEP(R, S, ICB, CUR) do {                                              \
    const int _po = ((R) / 3) * PW + ((R) % 3);                                 \
    short8 _bf[7];                                                              \
    _Pragma("unroll")                                                           \
    for (int nt = 0; nt < 7; ++nt) {                                            \
      int pr = basepos[nt] + _po;                                               \
      _bf[nt] = *(const short8*)&bpl[CUR][pr * 32 + ((quad ^ ((pr >> 1) & 3)) << 3)]; \
    }                                                                           \
    const int _kk2 = (ICB) * 9 + (R) + 2;                                       \
    const unsigned short* _w2 = wb + (size_t)_kk2 * 4096 + aoff;                \
    _Pragma("unroll")                                                           \
    for (int nt = 0; nt < 7; ++nt)                                              \
      acc[0][nt] = __builtin_amdgcn_mfma_f32_16x16x32_bf16(S##0, _bf[nt], acc[0][nt], 0, 0, 0); \
    if (_kk2 < 72) S##0 = *(const short8*)&_w2[0];                              \
    _Pragma("unroll")                                                           \
    for (int nt = 0; nt < 7; ++nt)                                              \
      acc[1][nt] = __builtin_amdgcn_mfma_f32_16x16x32_bf16(S##1, _bf[nt], acc[1][nt], 0, 0, 0); \
    if (_kk2 < 72) S##1 = *(const short8*)&_w2[512];                            \
    _Pragma("unroll")                                                           \
    for (int nt = 0; nt < 7; ++nt)                                              \
      acc[2][nt] = __builtin_amdgcn_mfma_f32_16x16x32_bf16(S##2, _bf[nt], acc[2][nt], 0, 0, 0); \
    if (_kk2 < 72) S##2 = *(const short8*)&_w2[1024];                           \
    _Pragma("unroll")                                                           \
    for (int nt = 0; nt < 7; ++nt)                                              \
      acc[3][nt] = __builtin_amdgcn_mfma_f32_16x16x32_bf16(S##3, _bf[nt], acc[3][nt], 0, 0, 0); \
    if (_kk2 < 72) S##3 = *(const short8*)&_w2[1536];                           \
  } while (0)

#pragma unroll 1
  for (int icb = 0; icb < 8; ++icb) {
    int cur = icb & 1;
    // async prefetch next icb's B-plane into the other buffer
    if (icb < 7) {
      for (int e = tid; e < 1392; e += 256)
        gll16(&xp[xbase + (size_t)(e >> 2) * 256 + (icb + 1) * 32 + (e & 3) * 8],
              &bpl[cur ^ 1][e * 8]);
    }
    // kk = icb*9 + r; even kk lives in afA, odd in afB (9 odd -> swap per icb)
    if (!(icb & 1)) {
      RSTEP(0, afA, icb, cur); RSTEP(1, afB, icb, cur); RSTEP(2, afA, icb, cur);
      RSTEP(3, afB, icb, cur); RSTEP(4, afA, icb, cur); RSTEP(5, afB, icb, cur);
      RSTEP(6, afA, icb, cur); RSTEP(7, afB, icb, cur); RSTEP(8, afA, icb, cur);
    } else {
      RSTEP(0, afB, icb, cur); RSTEP(1, afA, icb, cur); RSTEP(2, afB, icb, cur);
      RSTEP(3, afA, icb, cur); RSTEP(4, afB, icb, cur); RSTEP(5, afA, icb, cur);
      RSTEP(6, afB, icb, cur); RSTEP(7, afA, icb, cur); RSTEP(8, afB, icb, cur);
    }
    __syncthreads();  // drains B prefetch + in-flight A preloads; 8x/block
  }
#undef RSTEP

  // epilogue: D row = quad*4+reg (m), col = l16 (n)
#pragma unroll
  for (int mt = 0; mt < 4; ++mt) {
    int m = ocb * 128 + mw * 64 + mt * 16 + quad * 4;
#pragma unroll
    for (int nt = 0; nt < 7; ++nt) {
      int n = nw * 112 + nt * 16 + l16;
      int yy = y0 + n / 56, xx = n % 56;
      size_t o = (((size_t)b * 256 + m) * 56 + yy) * 56 + xx;
#pragma unroll
      for (int reg = 0; reg < 4; ++reg)
        out[o + (size_t)reg * PLANE] = acc[mt][nt][reg];
    }
  }
}

extern "C" void kernel_launch(void* const* d_in, const int* in_sizes, int n_in,
                              void* d_out, int out_size, void* d_ws, size_t ws_size,
                              hipStream_t stream) {
  const float* x    = (const float*)d_in[0];
  const float* w1   = (const float*)d_in[1];
  const float* b1   = (const float*)d_in[2];
  const float* w2   = (const float*)d_in[3];
  const float* b2   = (const float*)d_in[4];
  const float* watt = (const float*)d_in[5];
  const float* batt = (const float*)d_in[6];
  float* out = (float*)d_out;

  float* avgp = (float*)d_ws;                          // 204800 f32
  float* maxp = avgp + 204800;                         // 204800 f32
  unsigned short* Wbf = (unsigned short*)(maxp + 204800);  // 32*9*256*256 bf16
  unsigned short* xp  = Wbf + (size_t)32 * 9 * 256 * 256;  // 32*3364*256 bf16

  poolprep_kernel<<<BATCH * 64, 512, 0, stream>>>(x, avgp, maxp, xp);
  wcalc_kernel<<<BATCH * OCH, 256, 0, stream>>>(avgp, maxp, w1, b1, w2, b2, watt, batt, Wbf);
  border_kernel<<<BATCH * 228, 256, 0, stream>>>(xp);
  conv_kernel<<<BATCH * 2 * 14, 256, 0, stream>>>(xp, Wbf, out);
}

// Round 5
// 403.894 us; speedup vs baseline: 1.8345x; 1.8345x over previous
//
#include <hip/hip_runtime.h>
#include <hip/hip_bf16.h>

#define BATCH 32
#define CIN   256
#define OCH   256
#define HW    56
#define PW    58
#define PAREA (PW*PW)   /* 3364 */
#define PLANE (HW*HW)   /* 3136 */

typedef float float4v __attribute__((ext_vector_type(4)));
typedef short short8  __attribute__((ext_vector_type(8)));
typedef short short4v __attribute__((ext_vector_type(4)));

__device__ __forceinline__ unsigned short f2bf(float f) {
  union { float f; unsigned u; } v; v.f = f;
  unsigned r = v.u + 0x7fffu + ((v.u >> 16) & 1u);
  return (unsigned short)(r >> 16);
}

// async global->LDS, 16B per lane, LDS dest linear in lane order
__device__ __forceinline__ void gll16(const unsigned short* g, unsigned short* l) {
  __builtin_amdgcn_global_load_lds(
      (const __attribute__((address_space(1))) void*)g,
      (__attribute__((address_space(3))) void*)l,
      16, 0, 0);
}

// ---------------- Kernel 1: fused pool (avg+max 56x56->5x5) + xp prep -----------
// block = (b, group of 4 channels), 512 thr, 50KB LDS -> 3 blocks/CU.
__global__ __launch_bounds__(512) void poolprep_kernel(
    const float* __restrict__ x, float* __restrict__ avgp,
    float* __restrict__ maxp, unsigned short* __restrict__ xp) {
  __shared__ float pl[4][3140];
  int p = blockIdx.x;                 // 2048 = 8 XCD * 256
  int L = (p & 7) * 256 + (p >> 3);
  int cg = L & 63, b = L >> 6;        // channels cg*4 .. cg*4+3
  int tid = threadIdx.x;
  const float* src = x + ((size_t)(b * 256 + cg * 4)) * PLANE;

  float4v v[7];
#pragma unroll
  for (int k = 0; k < 7; ++k) {
    int e = tid + k * 512;
    if (e < 3136) v[k] = *(const float4v*)&src[(size_t)(e / 784) * PLANE + (e % 784) * 4];
  }
#pragma unroll
  for (int k = 0; k < 7; ++k) {
    int e = tid + k * 512;
    if (e < 3136) *(float4v*)&pl[e / 784][(e % 784) * 4] = v[k];
  }
  __syncthreads();

  if (tid < 100) {
    int c = tid / 25, bin = tid % 25;
    int i = bin / 5, j = bin % 5;
    int r0 = (i * HW) / 5, r1 = ((i + 1) * HW + 4) / 5;
    int c0 = (j * HW) / 5, c1 = ((j + 1) * HW + 4) / 5;
    float s = 0.f, m = -1e30f;
    for (int r = r0; r < r1; ++r)
      for (int c2 = c0; c2 < c1; ++c2) {
        float vv = pl[c][r * HW + c2];
        s += vv; m = fmaxf(m, vv);
      }
    size_t o = ((size_t)(b * 256 + cg * 4 + c)) * 25 + bin;
    avgp[o] = s / (float)((r1 - r0) * (c1 - c0));
    maxp[o] = m;
  }

  // xp: bf16 [b][pos][ic], swizzled: 8-elem chunk c stored at c ^ ((pos>>1)&3)
  int ch0 = cg * 4;
  int g32 = ch0 >> 5;
  int cc = (ch0 >> 3) & 3;
  int half = (ch0 >> 2) & 1;
  for (int pi = tid; pi < PLANE; pi += 512) {
    int y = pi / 56, col = pi % 56;
    int pos = (y + 1) * PW + (col + 1);
    short4v w4;
#pragma unroll
    for (int k = 0; k < 4; ++k) w4[k] = (short)f2bf(pl[k][pi]);
    int cph = cc ^ ((pos >> 1) & 3);
    *(short4v*)&xp[((size_t)b * PAREA + pos) * 256 + g32 * 32 + cph * 8 + half * 4] = w4;
  }
}

// ---------------- Kernel 2: dynamic weight computation ----------------
// Wbf layout: tiles [b][ocb2][icb8][r9] of [oc 128][ic 32] (8KB/tile)
__global__ __launch_bounds__(256) void wcalc_kernel(
    const float* __restrict__ avgp, const float* __restrict__ maxp,
    const float* __restrict__ w1, const float* __restrict__ b1,
    const float* __restrict__ w2, const float* __restrict__ b2,
    const float* __restrict__ watt, const float* __restrict__ batt,
    unsigned short* __restrict__ Wbf) {
  int blk = blockIdx.x;
  int oc = blk & 255, b = blk >> 8;
  __shared__ float s_avg[25], s_max[25], s_w1[9], s_wgt1[9];
  int tid = threadIdx.x;
  size_t base = ((size_t)b * 256 + oc) * 25;
  if (tid < 25) { s_avg[tid] = avgp[base + tid]; s_max[tid] = maxp[base + tid]; }
  if (tid >= 32 && tid < 41) s_w1[tid - 32] = w1[oc * 9 + (tid - 32)];
  __syncthreads();
  if (tid < 9) {
    int ky = tid / 3, kx = tid % 3;
    float acc = b1[oc];
    for (int u = 0; u < 3; ++u)
      for (int v = 0; v < 3; ++v)
        acc += s_avg[(ky + u) * 5 + kx + v] * s_w1[u * 3 + v];
    s_wgt1[tid] = fmaxf(acc, 0.f);
  }
  __syncthreads();
  int ic = tid;
  size_t g = (size_t)oc * 256 + ic;
  float wa[9];
#pragma unroll
  for (int r = 0; r < 9; ++r) wa[r] = watt[g * 9 + r];
  float ba = batt[g], w2v = w2[g], b2v = b2[g];

  int ocb = oc >> 7, ocl = oc & 127;
  int icb = ic >> 5;
  size_t tilebase = ((size_t)((b * 2 + ocb) * 8 + icb)) * 9;
  size_t elem = (size_t)ocl * 32 + (ic & 31);

#pragma unroll
  for (int r = 0; r < 9; ++r) {
    int ky = r / 3, kx = r % 3;
    float s = ba;
#pragma unroll
    for (int u = 0; u < 3; ++u)
#pragma unroll
      for (int v = 0; v < 3; ++v)
        s += s_max[(ky + u) * 5 + kx + v] * wa[u * 3 + v];
    float att = 1.f / (1.f + __expf(-s));
    float wv = (s_wgt1[r] * w2v + b2v) * att;
    Wbf[(tilebase + r) * 4096 + elem] = f2bf(wv);
  }
}

// ---------------- Kernel 3a: zero the padded border of xp ----------------
__global__ __launch_bounds__(256) void border_kernel(unsigned short* __restrict__ xp) {
  int bid = blockIdx.x;           // 32 * 228
  int b = bid / 228, bi = bid % 228;
  int pos;
  if (bi < 58)       pos = bi;
  else if (bi < 116) pos = 57 * PW + (bi - 58);
  else if (bi < 172) pos = (bi - 116 + 1) * PW;
  else               pos = (bi - 172 + 1) * PW + 57;
  xp[((size_t)b * PAREA + pos) * 256 + threadIdx.x] = 0;
}

// ---------------- Kernel 4: dynamic conv via MFMA ------------------------------
// A: 2-deep register pipeline (copy-rotated, branch-free; compiler renames away
//    the copies). B: LDS double-buffered via global_load_lds; ONE barrier/icb.
__global__ __launch_bounds__(256, 2) void conv_kernel(
    const unsigned short* __restrict__ xp,
    const unsigned short* __restrict__ Wbf,
    float* __restrict__ out) {
  __shared__ unsigned short bpl[2][348 * 32];  // 2 x 22272 B, swizzled layout

  int p = blockIdx.x;
  int L = (p & 7) * 112 + (p >> 3);   // XCD-chunked: 4 batches per XCD
  int rt = L % 14; int t2 = L / 14; int ocb = t2 & 1; int b = t2 >> 1;
  int y0 = rt * 4;
  int tid = threadIdx.x;
  int lane = tid & 63, w = tid >> 6;
  int mw = w & 1, nw = w >> 1;     // 2 M-waves x 2 N-waves
  int quad = lane >> 4, l16 = lane & 15;

  int basepos[7];
#pragma unroll
  for (int nt = 0; nt < 7; ++nt) {
    int n = nw * 112 + nt * 16 + l16;
    basepos[nt] = (n / 56) * PW + (n % 56);
  }

  float4v acc[4][7];
#pragma unroll
  for (int mt = 0; mt < 4; ++mt)
#pragma unroll
    for (int nt = 0; nt < 7; ++nt)
      acc[mt][nt] = (float4v){0.f, 0.f, 0.f, 0.f};

  const size_t xbase = ((size_t)b * PAREA + (size_t)y0 * PW) * 256;
  const unsigned short* wb = Wbf + (size_t)((b * 2 + ocb) * 72) * 4096;
  const int aoff = (mw * 64 + l16) * 32 + quad * 8;   // + mt*512 per m-tile

  // prologue: stage bpl[0] (icb=0); preload A slice kk=0 -> af, kk=1 -> an
  for (int e = tid; e < 1392; e += 256)
    gll16(&xp[xbase + (size_t)(e >> 2) * 256 + (e & 3) * 8], &bpl[0][e * 8]);
  short8 af0, af1, af2, af3, an0, an1, an2, an3;
  {
    const unsigned short* w0p = wb + aoff;
    af0 = *(const short8*)&w0p[0];    af1 = *(const short8*)&w0p[512];
    af2 = *(const short8*)&w0p[1024]; af3 = *(const short8*)&w0p[1536];
    const unsigned short* w1p = wb + 4096 + aoff;
    an0 = *(const short8*)&w1p[0];    an1 = *(const short8*)&w1p[512];
    an2 = *(const short8*)&w1p[1024]; an3 = *(const short8*)&w1p[1536];
  }
  __syncthreads();

  // One r-step: nt-outer (1 live bfrag), consume af (slice kk), rotate af<-an,
  // issue an <- slice kk+2. DO2 is a compile-time constant.
#define RSTEP(R, ICB, CUR, DO2) do {                                            \
    const int _po = ((R) / 3) * PW + ((R) % 3);                                 \
    _Pragma("unroll")                                                           \
    for (int nt = 0; nt < 7; ++nt) {                                            \
      int pr = basepos[nt] + _po;                                               \
      short8 _bf = *(const short8*)&bpl[CUR][pr * 32 + ((quad ^ ((pr >> 1) & 3)) << 3)]; \
      acc[0][nt] = __builtin_amdgcn_mfma_f32_16x16x32_bf16(af0, _bf, acc[0][nt], 0, 0, 0); \
      acc[1][nt] = __builtin_amdgcn_mfma_f32_16x16x32_bf16(af1, _bf, acc[1][nt], 0, 0, 0); \
      acc[2][nt] = __builtin_amdgcn_mfma_f32_16x16x32_bf16(af2, _bf, acc[2][nt], 0, 0, 0); \
      acc[3][nt] = __builtin_amdgcn_mfma_f32_16x16x32_bf16(af3, _bf, acc[3][nt], 0, 0, 0); \
    }                                                                           \
    af0 = an0; af1 = an1; af2 = an2; af3 = an3;                                 \
    if (DO2) {                                                                  \
      const unsigned short* _w = wb + (size_t)((ICB) * 9 + (R) + 2) * 4096 + aoff; \
      an0 = *(const short8*)&_w[0];    an1 = *(const short8*)&_w[512];          \
      an2 = *(const short8*)&_w[1024]; an3 = *(const short8*)&_w[1536];         \
    }                                                                           \
  } while (0)

#pragma unroll 1
  for (int icb = 0; icb < 7; ++icb) {
    int cur = icb & 1;
    // async prefetch next icb's B-plane into the other buffer (always valid here)
    for (int e = tid; e < 1392; e += 256)
      gll16(&xp[xbase + (size_t)(e >> 2) * 256 + (icb + 1) * 32 + (e & 3) * 8],
            &bpl[cur ^ 1][e * 8]);
    RSTEP(0, icb, cur, 1); RSTEP(1, icb, cur, 1); RSTEP(2, icb, cur, 1);
    RSTEP(3, icb, cur, 1); RSTEP(4, icb, cur, 1); RSTEP(5, icb, cur, 1);
    RSTEP(6, icb, cur, 1); RSTEP(7, icb, cur, 1); RSTEP(8, icb, cur, 1);
    __syncthreads();  // drains B prefetch; 7x/block
  }
  // peeled icb = 7 (cur = 1): no B prefetch; A reloads only while kk+2 <= 71
  RSTEP(0, 7, 1, 1); RSTEP(1, 7, 1, 1); RSTEP(2, 7, 1, 1);
  RSTEP(3, 7, 1, 1); RSTEP(4, 7, 1, 1); RSTEP(5, 7, 1, 1);
  RSTEP(6, 7, 1, 1); RSTEP(7, 7, 1, 0); RSTEP(8, 7, 1, 0);
#undef RSTEP

  // epilogue: D row = quad*4+reg (m), col = l16 (n)
#pragma unroll
  for (int mt = 0; mt < 4; ++mt) {
    int m = ocb * 128 + mw * 64 + mt * 16 + quad * 4;
#pragma unroll
    for (int nt = 0; nt < 7; ++nt) {
      int n = nw * 112 + nt * 16 + l16;
      int yy = y0 + n / 56, xx = n % 56;
      size_t o = (((size_t)b * 256 + m) * 56 + yy) * 56 + xx;
#pragma unroll
      for (int reg = 0; reg < 4; ++reg)
        out[o + (size_t)reg * PLANE] = acc[mt][nt][reg];
    }
  }
}

extern "C" void kernel_launch(void* const* d_in, const int* in_sizes, int n_in,
                              void* d_out, int out_size, void* d_ws, size_t ws_size,
                              hipStream_t stream) {
  const float* x    = (const float*)d_in[0];
  const float* w1   = (const float*)d_in[1];
  const float* b1   = (const float*)d_in[2];
  const float* w2   = (const float*)d_in[3];
  const float* b2   = (const float*)d_in[4];
  const float* watt = (const float*)d_in[5];
  const float* batt = (const float*)d_in[6];
  float* out = (float*)d_out;

  float* avgp = (float*)d_ws;                          // 204800 f32
  float* maxp = avgp + 204800;                         // 204800 f32
  unsigned short* Wbf = (unsigned short*)(maxp + 204800);  // 32*9*256*256 bf16
  unsigned short* xp  = Wbf + (size_t)32 * 9 * 256 * 256;  // 32*3364*256 bf16

  poolprep_kernel<<<BATCH * 64, 512, 0, stream>>>(x, avgp, maxp, xp);
  wcalc_kernel<<<BATCH * OCH, 256, 0, stream>>>(avgp, maxp, w1, b1, w2, b2, watt, batt, Wbf);
  border_kernel<<<BATCH * 228, 256, 0, stream>>>(xp);
  conv_kernel<<<BATCH * 2 * 14, 256, 0, stream>>>(xp, Wbf, out);
}